// Round 5
// baseline (326.506 us; speedup 1.0000x reference)
//
#include <hip/hip_runtime.h>
#include <math.h>

#define B_ 32
#define T_ 1024
#define D_ 512
#define U_ 64
#define TS_ 4          // t-reduction split in K1
#define TH_ (T_/TS_)   // 256
#define TC_ 32         // K1 t-chunk staged in LDS
#define TT_ 64         // K2 t-tile
#define SR_ 10.0f
#define EPS_ 1e-7f

typedef __attribute__((ext_vector_type(8))) short bf16x8;
typedef __attribute__((ext_vector_type(8))) unsigned short u16x8;
typedef __attribute__((ext_vector_type(4))) float f32x4;

#define LSTRIDE 40     // ushorts per LDS row: 32 t + 8 pad; (5*row+lg)%8 covers all 16B slots evenly

__device__ __forceinline__ uint pack_hi2(float e, float o) {
    return (__float_as_uint(e) >> 16) | (__float_as_uint(o) & 0xffff0000u);
}
__device__ __forceinline__ float hi_part(float v) {
    return __uint_as_float(__float_as_uint(v) & 0xffff0000u);
}
// packed M plane: low ushort = hi-bf16, high ushort = lo-bf16
__device__ __forceinline__ uint packM(float s) {
    uint hb = __float_as_uint(s) & 0xffff0000u;
    float l = s - __uint_as_float(hb);
    return (hb >> 16) | (__float_as_uint(l) & 0xffff0000u);
}

// ---------------------------------------------------------------------------
// K0: one-shot transpose+split of w2,w3 -> wT[plane][64u][1024t] bf16 ushorts
// planes: 0=w2h 1=w2l 2=w3h 3=w3l. 512 KB total, L2-resident for k1.
// ---------------------------------------------------------------------------
__global__ __launch_bounds__(256) void k0_wsplit(
    const float* __restrict__ w2, const float* __restrict__ w3,
    ushort* __restrict__ wT)
{
    __shared__ float tA[64*65];
    __shared__ float tB[64*65];
    const int t0  = blockIdx.x * 64;
    const int tid = threadIdx.x;
    const int tl  = tid >> 2;        // 0..63 t-row
    const int q   = tid & 3;
    #pragma unroll
    for (int k = 0; k < 4; ++k) {
        int f4 = q*4 + k;
        float4 a = *(const float4*)&w2[(size_t)(t0+tl)*U_ + f4*4];
        float4 b = *(const float4*)&w3[(size_t)(t0+tl)*U_ + f4*4];
        tA[tl*65 + f4*4+0] = a.x; tA[tl*65 + f4*4+1] = a.y;
        tA[tl*65 + f4*4+2] = a.z; tA[tl*65 + f4*4+3] = a.w;
        tB[tl*65 + f4*4+0] = b.x; tB[tl*65 + f4*4+1] = b.y;
        tB[tl*65 + f4*4+2] = b.z; tB[tl*65 + f4*4+3] = b.w;
    }
    __syncthreads();
    const int u   = tid >> 2;        // 0..63
    const int ts4 = tid & 3;
    #pragma unroll
    for (int k = 0; k < 4; ++k) {
        int tb = ts4*16 + k*4;       // 4 consecutive t
        float vA[4], vB[4];
        #pragma unroll
        for (int i = 0; i < 4; ++i) { vA[i] = tA[(tb+i)*65 + u]; vB[i] = tB[(tb+i)*65 + u]; }
        uint2 hA = { pack_hi2(vA[0], vA[1]), pack_hi2(vA[2], vA[3]) };
        uint2 lA = { pack_hi2(vA[0]-hi_part(vA[0]), vA[1]-hi_part(vA[1])),
                     pack_hi2(vA[2]-hi_part(vA[2]), vA[3]-hi_part(vA[3])) };
        uint2 hB = { pack_hi2(vB[0], vB[1]), pack_hi2(vB[2], vB[3]) };
        uint2 lB = { pack_hi2(vB[0]-hi_part(vB[0]), vB[1]-hi_part(vB[1])),
                     pack_hi2(vB[2]-hi_part(vB[2]), vB[3]-hi_part(vB[3])) };
        *(uint2*)&wT[(size_t)(0*64 + u)*1024 + t0 + tb] = hA;
        *(uint2*)&wT[(size_t)(1*64 + u)*1024 + t0 + tb] = lA;
        *(uint2*)&wT[(size_t)(2*64 + u)*1024 + t0 + tb] = hB;
        *(uint2*)&wT[(size_t)(3*64 + u)*1024 + t0 + tb] = lB;
    }
}

// ---------------------------------------------------------------------------
// K1 (MFMA): per (b, d-tile 64, t-quarter) compute
//   P[ts][b][0][d][u] += sum_t x1*w3 + x2*w2   (M1 part)
//   P[ts][b][1][d][u] += sum_t x1*w2 + x2*w3   (M2 part)
// bf16-split 3-term emulation on v_mfma_f32_16x16x32_bf16.
// x staged via float4 reads + split/pack; w staged as pure ushort8 copies
// from pre-split wT planes (no VALU). LDS layout & MFMA identical to R2.
// ---------------------------------------------------------------------------
__global__ __launch_bounds__(256, 4) void k1_partials(
    const float* __restrict__ x1, const float* __restrict__ x2,
    const ushort* __restrict__ wT, float* __restrict__ P)
{
    __shared__ ushort lds[8][64*LSTRIDE];  // x1h,x1l,x2h,x2l,w2h,w2l,w3h,w3l (40 KiB)

    const int dt  = blockIdx.x;       // 0..7
    const int ts  = blockIdx.y;       // 0..TS_-1
    const int b   = blockIdx.z;       // 0..31
    const int d0  = dt * 64;
    const int tid = threadIdx.x;
    const int lane = tid & 63;
    const int wid  = tid >> 6;        // 0..3
    const int wd   = wid & 1;         // d-half (32 rows)
    const int wu   = wid >> 1;        // u-half (32 cols)
    const int lr   = lane & 15;       // frag row/col within 16
    const int lg   = lane >> 4;       // k-group 0..3
    // x staging decomposition
    const int tp   = tid >> 4;        // 0..15 : t-pair
    const int f4   = tid & 15;        // float4 col
    // w staging decomposition
    const int wp   = tid >> 6;        // plane 0..3
    const int wur  = (tid & 63) >> 2; // 0..15
    const int wtq  = tid & 3;         // 8-ushort t-quad

    f32x4 acc1[2][2], acc2[2][2];
    const f32x4 z = {0.f, 0.f, 0.f, 0.f};
    #pragma unroll
    for (int mi = 0; mi < 2; ++mi)
        #pragma unroll
        for (int ni = 0; ni < 2; ++ni) { acc1[mi][ni] = z; acc2[mi][ni] = z; }

    const size_t xb = (size_t)b * T_ * D_;

    for (int c = 0; c < TH_/TC_; ++c) {
        const int tb = ts*TH_ + c*TC_;
        // ---- x staging: 2 arrays, float4 reads, split+pack t-pairs
        #pragma unroll
        for (int a = 0; a < 2; ++a) {
            const float* xa = a ? x2 : x1;
            float4 ve = *(const float4*)&xa[xb + (size_t)(tb + 2*tp    )*D_ + d0 + f4*4];
            float4 vo = *(const float4*)&xa[xb + (size_t)(tb + 2*tp + 1)*D_ + d0 + f4*4];
            uint* hb = (uint*)lds[a*2];
            uint* lb = (uint*)lds[a*2+1];
            float ev[4] = {ve.x, ve.y, ve.z, ve.w};
            float ov[4] = {vo.x, vo.y, vo.z, vo.w};
            #pragma unroll
            for (int k = 0; k < 4; ++k) {
                float e = ev[k], o = ov[k];
                int idx = (f4*4 + k)*(LSTRIDE/2) + tp;
                hb[idx] = pack_hi2(e, o);
                lb[idx] = pack_hi2(e - hi_part(e), o - hi_part(o));
            }
        }
        // ---- w staging: pure copy from pre-split planes
        {
            const ushort* wsrc = wT + (size_t)wp*64*1024;
            #pragma unroll
            for (int j = 0; j < 4; ++j) {
                int u = j*16 + wur;
                u16x8 v = *(const u16x8*)&wsrc[(size_t)u*1024 + tb + wtq*8];
                *(u16x8*)&lds[4+wp][u*LSTRIDE + wtq*8] = v;
            }
        }
        __syncthreads();
        // ---- fragment loads (ds_read_b128, 16B-aligned)
        bf16x8 A1h[2], A1l[2], A2h[2], A2l[2];
        bf16x8 B2h[2], B2l[2], B3h[2], B3l[2];
        #pragma unroll
        for (int mi = 0; mi < 2; ++mi) {
            int off = (32*wd + 16*mi + lr)*LSTRIDE + 8*lg;
            A1h[mi] = *(const bf16x8*)&lds[0][off];
            A1l[mi] = *(const bf16x8*)&lds[1][off];
            A2h[mi] = *(const bf16x8*)&lds[2][off];
            A2l[mi] = *(const bf16x8*)&lds[3][off];
        }
        #pragma unroll
        for (int ni = 0; ni < 2; ++ni) {
            int off = (32*wu + 16*ni + lr)*LSTRIDE + 8*lg;
            B2h[ni] = *(const bf16x8*)&lds[4][off];
            B2l[ni] = *(const bf16x8*)&lds[5][off];
            B3h[ni] = *(const bf16x8*)&lds[6][off];
            B3l[ni] = *(const bf16x8*)&lds[7][off];
        }
        // ---- MFMA: 48 per wave per chunk
        #pragma unroll
        for (int mi = 0; mi < 2; ++mi)
            #pragma unroll
            for (int ni = 0; ni < 2; ++ni) {
                f32x4 c1 = acc1[mi][ni];
                f32x4 c2 = acc2[mi][ni];
                c1 = __builtin_amdgcn_mfma_f32_16x16x32_bf16(A1h[mi], B3h[ni], c1, 0, 0, 0);
                c1 = __builtin_amdgcn_mfma_f32_16x16x32_bf16(A1h[mi], B3l[ni], c1, 0, 0, 0);
                c1 = __builtin_amdgcn_mfma_f32_16x16x32_bf16(A1l[mi], B3h[ni], c1, 0, 0, 0);
                c1 = __builtin_amdgcn_mfma_f32_16x16x32_bf16(A2h[mi], B2h[ni], c1, 0, 0, 0);
                c1 = __builtin_amdgcn_mfma_f32_16x16x32_bf16(A2h[mi], B2l[ni], c1, 0, 0, 0);
                c1 = __builtin_amdgcn_mfma_f32_16x16x32_bf16(A2l[mi], B2h[ni], c1, 0, 0, 0);
                c2 = __builtin_amdgcn_mfma_f32_16x16x32_bf16(A1h[mi], B2h[ni], c2, 0, 0, 0);
                c2 = __builtin_amdgcn_mfma_f32_16x16x32_bf16(A1h[mi], B2l[ni], c2, 0, 0, 0);
                c2 = __builtin_amdgcn_mfma_f32_16x16x32_bf16(A1l[mi], B2h[ni], c2, 0, 0, 0);
                c2 = __builtin_amdgcn_mfma_f32_16x16x32_bf16(A2h[mi], B3h[ni], c2, 0, 0, 0);
                c2 = __builtin_amdgcn_mfma_f32_16x16x32_bf16(A2h[mi], B3l[ni], c2, 0, 0, 0);
                c2 = __builtin_amdgcn_mfma_f32_16x16x32_bf16(A2l[mi], B3h[ni], c2, 0, 0, 0);
                acc1[mi][ni] = c1;
                acc2[mi][ni] = c2;
            }
        __syncthreads();
    }

    // ---- epilogue: C/D layout col=lane&15, row=(lane>>4)*4+reg
    const size_t DU = (size_t)D_ * U_;
    const size_t base0 = (((size_t)ts*B_ + b)*2)*DU;
    #pragma unroll
    for (int mi = 0; mi < 2; ++mi)
        #pragma unroll
        for (int ni = 0; ni < 2; ++ni) {
            const int d = d0 + 32*wd + 16*mi + 4*lg;
            const int u = 32*wu + 16*ni + lr;
            #pragma unroll
            for (int r = 0; r < 4; ++r) {
                P[base0 + (size_t)(d+r)*U_ + u]      = acc1[mi][ni][r];
                P[base0 + DU + (size_t)(d+r)*U_ + u] = acc2[mi][ni][r];
            }
        }
}

// ---------------------------------------------------------------------------
// K1b: M = w1 + sum_ts P; output as packed hi|lo bf16 uint planes for K2.
// ---------------------------------------------------------------------------
__global__ __launch_bounds__(256) void k1_combine(
    const float* __restrict__ P, const float* __restrict__ w1,
    uint* __restrict__ Mhl1, uint* __restrict__ Mhl2)
{
    const int n = blockIdx.x*256 + threadIdx.x;   // 0 .. B*D*U/4-1
    const int b = n >> 13;                        // D*U/4 = 8192
    const int r = n & 8191;
    const size_t du = (size_t)r * 4;
    const size_t DU = (size_t)D_ * U_;
    float4 w = *(const float4*)&w1[du];
    float4 s1 = w, s2 = w;
    #pragma unroll
    for (int ts = 0; ts < TS_; ++ts) {
        const float* Pb = P + (((size_t)ts*B_ + b)*2)*DU + du;
        float4 a = *(const float4*)&Pb[0];
        float4 c = *(const float4*)&Pb[DU];
        s1.x += a.x; s1.y += a.y; s1.z += a.z; s1.w += a.w;
        s2.x += c.x; s2.y += c.y; s2.z += c.z; s2.w += c.w;
    }
    uint4 m1 = { packM(s1.x), packM(s1.y), packM(s1.z), packM(s1.w) };
    uint4 m2 = { packM(s2.x), packM(s2.y), packM(s2.z), packM(s2.w) };
    *(uint4*)&Mhl1[(size_t)b*DU + du] = m1;
    *(uint4*)&Mhl2[(size_t)b*DU + du] = m2;
}

// ---------------------------------------------------------------------------
// K2 (MFMA): eij[br][b][t] = SR * sum_u tanh( H[t,u] ) * we[u],
//   H = x[b] @ M[br][b]. M comes pre-split as packed hi|lo uint planes ->
// staging is load+unpack+b128 write, no float split math. x staged as before.
// XOR swizzle byte ^= (row&7)<<4 on write and read (both tiles, 128B rows).
// ---------------------------------------------------------------------------
__global__ __launch_bounds__(256, 4) void k2_eij(
    const float* __restrict__ x1, const float* __restrict__ x2,
    const uint* __restrict__ Mhl1, const uint* __restrict__ Mhl2,
    const float* __restrict__ we, float* __restrict__ eij)
{
    __shared__ ushort xh[64*64];   // 8 KiB each; 32 KiB total
    __shared__ ushort xl[64*64];
    __shared__ ushort mh[64*64];
    __shared__ ushort ml[64*64];

    const int tt = blockIdx.x;       // 0..15
    const int b  = blockIdx.y;       // 0..31
    const int br = blockIdx.z;       // 0..1
    const float* x = br ? x2 : x1;
    const uint* M  = (br ? Mhl2 : Mhl1) + (size_t)b * D_ * U_;
    const int tid  = threadIdx.x;
    const int lane = tid & 63;
    const int wid  = tid >> 6;       // wave -> t-row block (16 rows)
    const int lr   = lane & 15;
    const int lg   = lane >> 4;

    const int s_tl = tid >> 4;       // 0..15 : t row (x stage)
    const int s_f4 = tid & 15;       // float4 col within 64-d chunk
    const int m_u  = tid & 63;       // u column (M stage)
    const int m_dq = tid >> 6;       // 0..3 : 16-d slice

    f32x4 acc[4];
    const f32x4 z = {0.f, 0.f, 0.f, 0.f};
    #pragma unroll
    for (int ni = 0; ni < 4; ++ni) acc[ni] = z;

    float wreg[4];
    #pragma unroll
    for (int ni = 0; ni < 4; ++ni) wreg[ni] = we[ni*16 + lr];

    const size_t xbase = ((size_t)b*T_ + (size_t)tt*64) * D_;

    for (int c = 0; c < D_/64; ++c) {
        const int d0 = c*64;
        // ---- x tile: [64 t][64 d] hi/lo, swizzled
        #pragma unroll
        for (int j = 0; j < 4; ++j) {
            int t = j*16 + s_tl;
            float4 v = *(const float4*)&x[xbase + (size_t)t*D_ + d0 + s_f4*4];
            float hx = hi_part(v.x), hy = hi_part(v.y), hz = hi_part(v.z), hw = hi_part(v.w);
            uint h0 = pack_hi2(v.x, v.y), h1 = pack_hi2(v.z, v.w);
            uint l0 = pack_hi2(v.x - hx, v.y - hy);
            uint l1 = pack_hi2(v.z - hz, v.w - hw);
            int cu  = s_f4*2;
            int swz = (t & 7) << 2;           // uint-granule XOR of byte-bit-4..6
            ((uint*)xh)[t*32 + ((cu  ) ^ swz)] = h0;
            ((uint*)xh)[t*32 + ((cu+1) ^ swz)] = h1;
            ((uint*)xl)[t*32 + ((cu  ) ^ swz)] = l0;
            ((uint*)xl)[t*32 + ((cu+1) ^ swz)] = l1;
        }
        // ---- M tile: [64 u][64 d] from packed planes (unpack only), swizzled
        #pragma unroll
        for (int k = 0; k < 2; ++k) {
            u16x8 hv, lv;
            #pragma unroll
            for (int j = 0; j < 8; ++j) {
                uint mm = M[(size_t)(d0 + m_dq*16 + k*8 + j)*U_ + m_u];
                hv[j] = (ushort)(mm & 0xffffu);
                lv[j] = (ushort)(mm >> 16);
            }
            int slot = (m_dq*2 + k) ^ (m_u & 7);
            *(u16x8*)&mh[m_u*64 + slot*8] = hv;
            *(u16x8*)&ml[m_u*64 + slot*8] = lv;
        }
        __syncthreads();
        // ---- MFMA: per wave 2 kk x 4 ni x 3 = 24 per chunk
        #pragma unroll
        for (int kk = 0; kk < 2; ++kk) {
            const int ar   = wid*16 + lr;
            const int aoff = ar*64 + (((lg + 4*kk)*8) ^ ((ar & 7) << 3));
            bf16x8 Ah = *(const bf16x8*)&xh[aoff];
            bf16x8 Al = *(const bf16x8*)&xl[aoff];
            #pragma unroll
            for (int ni = 0; ni < 4; ++ni) {
                const int bu   = ni*16 + lr;
                const int boff = bu*64 + (((lg + 4*kk)*8) ^ ((bu & 7) << 3));
                bf16x8 Bh = *(const bf16x8*)&mh[boff];
                bf16x8 Bl = *(const bf16x8*)&ml[boff];
                f32x4 a = acc[ni];
                a = __builtin_amdgcn_mfma_f32_16x16x32_bf16(Ah, Bh, a, 0, 0, 0);
                a = __builtin_amdgcn_mfma_f32_16x16x32_bf16(Ah, Bl, a, 0, 0, 0);
                a = __builtin_amdgcn_mfma_f32_16x16x32_bf16(Al, Bh, a, 0, 0, 0);
                acc[ni] = a;
            }
        }
        __syncthreads();
    }

    // ---- epilogue: row=(lane>>4)*4+r, col=ni*16+lr
    #pragma unroll
    for (int r = 0; r < 4; ++r) {
        float s = 0.f;
        #pragma unroll
        for (int ni = 0; ni < 4; ++ni) s += tanhf(acc[ni][r]) * wreg[ni];
        s += __shfl_xor(s, 1);
        s += __shfl_xor(s, 2);
        s += __shfl_xor(s, 4);
        s += __shfl_xor(s, 8);
        if (lr == 0) {
            int t = tt*64 + wid*16 + lg*4 + r;
            eij[((size_t)br*B_ + b)*T_ + t] = SR_ * s;
        }
    }
}

// ---------------------------------------------------------------------------
// K45: fused softmax + scale (unchanged).
// ---------------------------------------------------------------------------
__global__ __launch_bounds__(256) void k45_scale(
    const float* __restrict__ x1, const float* __restrict__ x2,
    const float* __restrict__ eij, float* __restrict__ out)
{
    __shared__ float sdata[256];
    __shared__ float wws[T_];

    const int tt = blockIdx.x;       // 0..15 : t-chunk of 64
    const int b  = blockIdx.y;       // 0..31
    const int br = blockIdx.z;       // 0..1
    const int tid = threadIdx.x;
    const float* e = eij + ((size_t)br*B_ + b) * T_;

    float v[4];
    float m = -1e30f;
    #pragma unroll
    for (int i = 0; i < 4; ++i) { v[i] = e[tid + i*256]; m = fmaxf(m, v[i]); }
    sdata[tid] = m; __syncthreads();
    for (int s = 128; s > 0; s >>= 1) {
        if (tid < s) sdata[tid] = fmaxf(sdata[tid], sdata[tid+s]);
        __syncthreads();
    }
    m = sdata[0]; __syncthreads();
    float ssum = 0.f;
    #pragma unroll
    for (int i = 0; i < 4; ++i) { v[i] = expf(v[i] - m); ssum += v[i]; }
    sdata[tid] = ssum; __syncthreads();
    for (int s = 128; s > 0; s >>= 1) {
        if (tid < s) sdata[tid] += sdata[tid+s];
        __syncthreads();
    }
    const float inv = 1.0f / (sdata[0] + EPS_ * expf(-m));
    #pragma unroll
    for (int i = 0; i < 4; ++i) wws[tid + i*256] = v[i] * inv;
    __syncthreads();

    const float* x = br ? x2 : x1;
    const size_t xb4 = ((size_t)b*T_ + (size_t)tt*64) * (D_/4);
    float* o = out + (size_t)br*B_*T_*D_;
    #pragma unroll
    for (int k = 0; k < 32; ++k) {
        int idx = k*256 + tid;           // 0..8191
        int tl  = idx >> 7;              // 0..63
        float w = wws[tt*64 + tl];
        float4 xv = ((const float4*)x)[xb4 + idx];
        float4 ov = {xv.x*w, xv.y*w, xv.z*w, xv.w*w};
        ((float4*)o)[xb4 + idx] = ov;
    }
}

// ---------------------------------------------------------------------------
extern "C" void kernel_launch(void* const* d_in, const int* in_sizes, int n_in,
                              void* d_out, int out_size, void* d_ws, size_t ws_size,
                              hipStream_t stream)
{
    const float* x1 = (const float*)d_in[0];
    const float* x2 = (const float*)d_in[1];
    const float* w1 = (const float*)d_in[2];
    const float* w2 = (const float*)d_in[3];
    const float* w3 = (const float*)d_in[4];
    const float* we = (const float*)d_in[5];
    float* out = (float*)d_out;
    float* ws  = (float*)d_ws;

    // workspace layout (float slots)
    float* P    = ws;                                  // 8,388,608
    uint*  Mhl1 = (uint*)(ws + (size_t)TS_*B_*2*D_*U_);    // 1,048,576 uints
    uint*  Mhl2 = Mhl1 + (size_t)B_*D_*U_;                 // 1,048,576 uints
    float* eij  = (float*)(Mhl2 + (size_t)B_*D_*U_);       // 65,536 floats
    ushort* wT  = (ushort*)(eij + (size_t)2*B_*T_);        // 262,144 ushorts

    k0_wsplit  <<<dim3(16), 256, 0, stream>>>(w2, w3, wT);
    k1_partials<<<dim3(8, TS_, B_), 256, 0, stream>>>(x1, x2, wT, P);
    k1_combine <<<dim3((B_*D_*U_/4 + 255)/256), 256, 0, stream>>>(P, w1, Mhl1, Mhl2);
    k2_eij     <<<dim3(T_/TT_, B_, 2), 256, 0, stream>>>(x1, x2, Mhl1, Mhl2, we, eij);
    k45_scale  <<<dim3(16, B_, 2), 256, 0, stream>>>(x1, x2, eij, out);
}

// Round 6
// 318.659 us; speedup vs baseline: 1.0246x; 1.0246x over previous
//
#include <hip/hip_runtime.h>
#include <math.h>

#define B_ 32
#define T_ 1024
#define D_ 512
#define U_ 64
#define TS_ 4          // t-reduction split in K1
#define TH_ (T_/TS_)   // 256
#define TC_ 32         // K1 t-chunk staged in LDS
#define NC_ (TH_/TC_)  // 8 chunks
#define TT_ 64         // K2 t-tile
#define SR_ 10.0f
#define EPS_ 1e-7f

typedef __attribute__((ext_vector_type(8))) short bf16x8;
typedef __attribute__((ext_vector_type(4))) float f32x4;

#define LSTRIDE 40     // ushorts per LDS row: 32 t + 8 pad; (5*row+lg)%8 covers all 16B slots evenly

__device__ __forceinline__ uint pack_hi2(float e, float o) {
    return (__float_as_uint(e) >> 16) | (__float_as_uint(o) & 0xffff0000u);
}
__device__ __forceinline__ float hi_part(float v) {
    return __uint_as_float(__float_as_uint(v) & 0xffff0000u);
}

// ---------------------------------------------------------------------------
// K1 (MFMA): per (b, d-tile 64, t-quarter) compute
//   P[ts][b][0][d][u] += sum_t x1*w3 + x2*w2   (M1 part)
//   P[ts][b][1][d][u] += sum_t x1*w2 + x2*w3   (M2 part)
// bf16-split 3-term emulation on v_mfma_f32_16x16x32_bf16.
// T14 async-STAGE: chunk c+1's global loads are ISSUED before chunk c's MFMA
// phase (into regs), and written to LDS after the post-MFMA barrier — HBM
// latency hides under the MFMA phase. Barrier count unchanged (2/chunk).
// ---------------------------------------------------------------------------
__global__ __launch_bounds__(256, 3) void k1_partials(
    const float* __restrict__ x1, const float* __restrict__ x2,
    const float* __restrict__ w2, const float* __restrict__ w3,
    float* __restrict__ P)
{
    __shared__ ushort lds[8][64*LSTRIDE];  // x1h,x1l,x2h,x2l,w2h,w2l,w3h,w3l (40 KiB)

    const int dt  = blockIdx.x;       // 0..7
    const int ts  = blockIdx.y;       // 0..TS_-1
    const int b   = blockIdx.z;       // 0..31
    const int d0  = dt * 64;
    const int tid = threadIdx.x;
    const int lane = tid & 63;
    const int wid  = tid >> 6;        // 0..3
    const int wd   = wid & 1;         // d-half (32 rows)
    const int wu   = wid >> 1;        // u-half (32 cols)
    const int lr   = lane & 15;       // frag row/col within 16
    const int lg   = lane >> 4;       // k-group 0..3
    const int col  = tid & 63;        // staging feature column
    const int tq   = tid >> 6;        // staging t-subrange (8 t each)

    f32x4 acc1[2][2], acc2[2][2];
    const f32x4 z = {0.f, 0.f, 0.f, 0.f};
    #pragma unroll
    for (int mi = 0; mi < 2; ++mi)
        #pragma unroll
        for (int ni = 0; ni < 2; ++ni) { acc1[mi][ni] = z; acc2[mi][ni] = z; }

    const size_t xb = (size_t)b * T_ * D_;

    float stg[4][8];   // staged next-chunk values (held across MFMA phase)

    // ---- issue + write chunk 0
    {
        const int tb = ts*TH_ + 8*tq;
        const float* ga[4] = { x1 + xb + (size_t)tb*D_ + d0 + col,
                               x2 + xb + (size_t)tb*D_ + d0 + col,
                               w2 + (size_t)tb*U_ + col,
                               w3 + (size_t)tb*U_ + col };
        const int stra[4] = { D_, D_, U_, U_ };
        #pragma unroll
        for (int a = 0; a < 4; ++a)
            #pragma unroll
            for (int j = 0; j < 8; ++j) stg[a][j] = ga[a][(size_t)j * stra[a]];
    }
    #pragma unroll
    for (int a = 0; a < 4; ++a) {
        uint* hb = (uint*)lds[a*2];
        uint* lb = (uint*)lds[a*2+1];
        #pragma unroll
        for (int p = 0; p < 4; ++p) {
            float e = stg[a][2*p], o = stg[a][2*p+1];
            uint he = __float_as_uint(e) & 0xffff0000u;
            uint ho = __float_as_uint(o) & 0xffff0000u;
            int idx = col*(LSTRIDE/2) + 4*tq + p;
            hb[idx] = (he >> 16) | ho;
            lb[idx] = pack_hi2(e - __uint_as_float(he), o - __uint_as_float(ho));
        }
    }
    __syncthreads();

    for (int c = 0; c < NC_; ++c) {
        // ---- issue next chunk's loads (latency hides under MFMA below)
        if (c+1 < NC_) {
            const int tb = ts*TH_ + (c+1)*TC_ + 8*tq;
            const float* ga[4] = { x1 + xb + (size_t)tb*D_ + d0 + col,
                                   x2 + xb + (size_t)tb*D_ + d0 + col,
                                   w2 + (size_t)tb*U_ + col,
                                   w3 + (size_t)tb*U_ + col };
            const int stra[4] = { D_, D_, U_, U_ };
            #pragma unroll
            for (int a = 0; a < 4; ++a)
                #pragma unroll
                for (int j = 0; j < 8; ++j) stg[a][j] = ga[a][(size_t)j * stra[a]];
        }
        // ---- fragment loads (ds_read_b128, 16B-aligned)
        bf16x8 A1h[2], A1l[2], A2h[2], A2l[2];
        bf16x8 B2h[2], B2l[2], B3h[2], B3l[2];
        #pragma unroll
        for (int mi = 0; mi < 2; ++mi) {
            int off = (32*wd + 16*mi + lr)*LSTRIDE + 8*lg;
            A1h[mi] = *(const bf16x8*)&lds[0][off];
            A1l[mi] = *(const bf16x8*)&lds[1][off];
            A2h[mi] = *(const bf16x8*)&lds[2][off];
            A2l[mi] = *(const bf16x8*)&lds[3][off];
        }
        #pragma unroll
        for (int ni = 0; ni < 2; ++ni) {
            int off = (32*wu + 16*ni + lr)*LSTRIDE + 8*lg;
            B2h[ni] = *(const bf16x8*)&lds[4][off];
            B2l[ni] = *(const bf16x8*)&lds[5][off];
            B3h[ni] = *(const bf16x8*)&lds[6][off];
            B3l[ni] = *(const bf16x8*)&lds[7][off];
        }
        // ---- MFMA: 48 per wave per chunk
        #pragma unroll
        for (int mi = 0; mi < 2; ++mi)
            #pragma unroll
            for (int ni = 0; ni < 2; ++ni) {
                f32x4 c1 = acc1[mi][ni];
                f32x4 c2 = acc2[mi][ni];
                c1 = __builtin_amdgcn_mfma_f32_16x16x32_bf16(A1h[mi], B3h[ni], c1, 0, 0, 0);
                c1 = __builtin_amdgcn_mfma_f32_16x16x32_bf16(A1h[mi], B3l[ni], c1, 0, 0, 0);
                c1 = __builtin_amdgcn_mfma_f32_16x16x32_bf16(A1l[mi], B3h[ni], c1, 0, 0, 0);
                c1 = __builtin_amdgcn_mfma_f32_16x16x32_bf16(A2h[mi], B2h[ni], c1, 0, 0, 0);
                c1 = __builtin_amdgcn_mfma_f32_16x16x32_bf16(A2h[mi], B2l[ni], c1, 0, 0, 0);
                c1 = __builtin_amdgcn_mfma_f32_16x16x32_bf16(A2l[mi], B2h[ni], c1, 0, 0, 0);
                c2 = __builtin_amdgcn_mfma_f32_16x16x32_bf16(A1h[mi], B2h[ni], c2, 0, 0, 0);
                c2 = __builtin_amdgcn_mfma_f32_16x16x32_bf16(A1h[mi], B2l[ni], c2, 0, 0, 0);
                c2 = __builtin_amdgcn_mfma_f32_16x16x32_bf16(A1l[mi], B2h[ni], c2, 0, 0, 0);
                c2 = __builtin_amdgcn_mfma_f32_16x16x32_bf16(A2h[mi], B3h[ni], c2, 0, 0, 0);
                c2 = __builtin_amdgcn_mfma_f32_16x16x32_bf16(A2h[mi], B3l[ni], c2, 0, 0, 0);
                c2 = __builtin_amdgcn_mfma_f32_16x16x32_bf16(A2l[mi], B3h[ni], c2, 0, 0, 0);
                acc1[mi][ni] = c1;
                acc2[mi][ni] = c2;
            }
        __syncthreads();           // all waves done reading chunk c
        // ---- write next chunk (vmcnt wait auto-inserted on first reg use)
        if (c+1 < NC_) {
            #pragma unroll
            for (int a = 0; a < 4; ++a) {
                uint* hb = (uint*)lds[a*2];
                uint* lb = (uint*)lds[a*2+1];
                #pragma unroll
                for (int p = 0; p < 4; ++p) {
                    float e = stg[a][2*p], o = stg[a][2*p+1];
                    uint he = __float_as_uint(e) & 0xffff0000u;
                    uint ho = __float_as_uint(o) & 0xffff0000u;
                    int idx = col*(LSTRIDE/2) + 4*tq + p;
                    hb[idx] = (he >> 16) | ho;
                    lb[idx] = pack_hi2(e - __uint_as_float(he), o - __uint_as_float(ho));
                }
            }
        }
        __syncthreads();           // writes visible for next iteration
    }

    // ---- epilogue: C/D layout col=lane&15, row=(lane>>4)*4+reg
    const size_t DU = (size_t)D_ * U_;
    const size_t base0 = (((size_t)ts*B_ + b)*2)*DU;
    #pragma unroll
    for (int mi = 0; mi < 2; ++mi)
        #pragma unroll
        for (int ni = 0; ni < 2; ++ni) {
            const int d = d0 + 32*wd + 16*mi + 4*lg;
            const int u = 32*wu + 16*ni + lr;
            #pragma unroll
            for (int r = 0; r < 4; ++r) {
                P[base0 + (size_t)(d+r)*U_ + u]      = acc1[mi][ni][r];
                P[base0 + DU + (size_t)(d+r)*U_ + u] = acc2[mi][ni][r];
            }
        }
}

// ---------------------------------------------------------------------------
// K1b: M1 = w1 + sum_ts P[ts][b][0];  M2 = w1 + sum_ts P[ts][b][1]
// ---------------------------------------------------------------------------
__global__ __launch_bounds__(256) void k1_combine(
    const float* __restrict__ P, const float* __restrict__ w1,
    float* __restrict__ M1, float* __restrict__ M2)
{
    const int n = blockIdx.x*256 + threadIdx.x;   // 0 .. B*D*U/4-1
    const int b = n >> 13;                        // D*U/4 = 8192
    const int r = n & 8191;
    const size_t du = (size_t)r * 4;
    const size_t DU = (size_t)D_ * U_;
    float4 w = *(const float4*)&w1[du];
    float4 s1 = w, s2 = w;
    #pragma unroll
    for (int ts = 0; ts < TS_; ++ts) {
        const float* Pb = P + (((size_t)ts*B_ + b)*2)*DU + du;
        float4 a = *(const float4*)&Pb[0];
        float4 c = *(const float4*)&Pb[DU];
        s1.x += a.x; s1.y += a.y; s1.z += a.z; s1.w += a.w;
        s2.x += c.x; s2.y += c.y; s2.z += c.z; s2.w += c.w;
    }
    *(float4*)&M1[(size_t)b*DU + du] = s1;
    *(float4*)&M2[(size_t)b*DU + du] = s2;
}

// ---------------------------------------------------------------------------
// K2 (MFMA): eij[br][b][t] = SR * sum_u tanh( H[t,u] ) * we[u],
//   H = x[b] @ M[br][b]. bf16-split 3-term emulation; XOR swizzle
// byte ^= (row&7)<<4 on write and read (both tiles, 128B rows).
// T14 async-STAGE: next d-chunk's loads issued before MFMA, written after.
// ---------------------------------------------------------------------------
__global__ __launch_bounds__(256, 4) void k2_eij(
    const float* __restrict__ x1, const float* __restrict__ x2,
    const float* __restrict__ M1, const float* __restrict__ M2,
    const float* __restrict__ we, float* __restrict__ eij)
{
    __shared__ ushort xh[64*64];   // 8 KiB each; 32 KiB total
    __shared__ ushort xl[64*64];
    __shared__ ushort mh[64*64];
    __shared__ ushort ml[64*64];

    const int tt = blockIdx.x;       // 0..15
    const int b  = blockIdx.y;       // 0..31
    const int br = blockIdx.z;       // 0..1
    const float* x = br ? x2 : x1;
    const float* M = (br ? M2 : M1) + (size_t)b * D_ * U_;
    const int tid  = threadIdx.x;
    const int lane = tid & 63;
    const int wid  = tid >> 6;       // wave -> t-row block (16 rows)
    const int lr   = lane & 15;
    const int lg   = lane >> 4;

    const int s_tl = tid >> 4;       // 0..15 : t row (x stage)
    const int s_f4 = tid & 15;       // float4 col within 64-d chunk
    const int m_u  = tid & 63;       // u column (M stage)
    const int m_dq = tid >> 6;       // 0..3 : 16-d slice

    f32x4 acc[4];
    const f32x4 z = {0.f, 0.f, 0.f, 0.f};
    #pragma unroll
    for (int ni = 0; ni < 4; ++ni) acc[ni] = z;

    float wreg[4];
    #pragma unroll
    for (int ni = 0; ni < 4; ++ni) wreg[ni] = we[ni*16 + lr];

    const size_t xbase = ((size_t)b*T_ + (size_t)tt*64) * D_;

    float4 sx[4];     // staged x (next chunk)
    float  sm[16];    // staged M (next chunk)

    // ---- issue + write chunk 0
    #pragma unroll
    for (int j = 0; j < 4; ++j)
        sx[j] = *(const float4*)&x[xbase + (size_t)(j*16 + s_tl)*D_ + s_f4*4];
    #pragma unroll
    for (int j2 = 0; j2 < 8; ++j2) {
        sm[2*j2  ] = M[(size_t)(m_dq*16 + 2*j2    )*U_ + m_u];
        sm[2*j2+1] = M[(size_t)(m_dq*16 + 2*j2 + 1)*U_ + m_u];
    }
    #pragma unroll
    for (int j = 0; j < 4; ++j) {
        int t = j*16 + s_tl;
        float4 v = sx[j];
        uint h0 = pack_hi2(v.x, v.y), h1 = pack_hi2(v.z, v.w);
        uint l0 = pack_hi2(v.x - hi_part(v.x), v.y - hi_part(v.y));
        uint l1 = pack_hi2(v.z - hi_part(v.z), v.w - hi_part(v.w));
        int cu  = s_f4*2;
        int swz = (t & 7) << 2;
        ((uint*)xh)[t*32 + ((cu  ) ^ swz)] = h0;
        ((uint*)xh)[t*32 + ((cu+1) ^ swz)] = h1;
        ((uint*)xl)[t*32 + ((cu  ) ^ swz)] = l0;
        ((uint*)xl)[t*32 + ((cu+1) ^ swz)] = l1;
    }
    {
        int swz = (m_u & 7) << 2;
        #pragma unroll
        for (int j2 = 0; j2 < 8; ++j2) {
            float e = sm[2*j2], o = sm[2*j2+1];
            uint hm = pack_hi2(e, o);
            uint lm = pack_hi2(e - hi_part(e), o - hi_part(o));
            int cu = m_dq*8 + j2;
            ((uint*)mh)[m_u*32 + (cu ^ swz)] = hm;
            ((uint*)ml)[m_u*32 + (cu ^ swz)] = lm;
        }
    }
    __syncthreads();

    for (int c = 0; c < D_/64; ++c) {
        // ---- issue next chunk's loads
        if (c+1 < D_/64) {
            const int d1 = (c+1)*64;
            #pragma unroll
            for (int j = 0; j < 4; ++j)
                sx[j] = *(const float4*)&x[xbase + (size_t)(j*16 + s_tl)*D_ + d1 + s_f4*4];
            #pragma unroll
            for (int j2 = 0; j2 < 8; ++j2) {
                sm[2*j2  ] = M[(size_t)(d1 + m_dq*16 + 2*j2    )*U_ + m_u];
                sm[2*j2+1] = M[(size_t)(d1 + m_dq*16 + 2*j2 + 1)*U_ + m_u];
            }
        }
        // ---- MFMA: per wave 2 kk x 4 ni x 3 = 24 per chunk
        #pragma unroll
        for (int kk = 0; kk < 2; ++kk) {
            const int ar   = wid*16 + lr;
            const int aoff = ar*64 + (((lg + 4*kk)*8) ^ ((ar & 7) << 3));
            bf16x8 Ah = *(const bf16x8*)&xh[aoff];
            bf16x8 Al = *(const bf16x8*)&xl[aoff];
            #pragma unroll
            for (int ni = 0; ni < 4; ++ni) {
                const int bu   = ni*16 + lr;
                const int boff = bu*64 + (((lg + 4*kk)*8) ^ ((bu & 7) << 3));
                bf16x8 Bh = *(const bf16x8*)&mh[boff];
                bf16x8 Bl = *(const bf16x8*)&ml[boff];
                f32x4 a = acc[ni];
                a = __builtin_amdgcn_mfma_f32_16x16x32_bf16(Ah, Bh, a, 0, 0, 0);
                a = __builtin_amdgcn_mfma_f32_16x16x32_bf16(Ah, Bl, a, 0, 0, 0);
                a = __builtin_amdgcn_mfma_f32_16x16x32_bf16(Al, Bh, a, 0, 0, 0);
                acc[ni] = a;
            }
        }
        __syncthreads();           // all waves done reading chunk c
        // ---- write next chunk
        if (c+1 < D_/64) {
            #pragma unroll
            for (int j = 0; j < 4; ++j) {
                int t = j*16 + s_tl;
                float4 v = sx[j];
                uint h0 = pack_hi2(v.x, v.y), h1 = pack_hi2(v.z, v.w);
                uint l0 = pack_hi2(v.x - hi_part(v.x), v.y - hi_part(v.y));
                uint l1 = pack_hi2(v.z - hi_part(v.z), v.w - hi_part(v.w));
                int cu  = s_f4*2;
                int swz = (t & 7) << 2;
                ((uint*)xh)[t*32 + ((cu  ) ^ swz)] = h0;
                ((uint*)xh)[t*32 + ((cu+1) ^ swz)] = h1;
                ((uint*)xl)[t*32 + ((cu  ) ^ swz)] = l0;
                ((uint*)xl)[t*32 + ((cu+1) ^ swz)] = l1;
            }
            int swz = (m_u & 7) << 2;
            #pragma unroll
            for (int j2 = 0; j2 < 8; ++j2) {
                float e = sm[2*j2], o = sm[2*j2+1];
                uint hm = pack_hi2(e, o);
                uint lm = pack_hi2(e - hi_part(e), o - hi_part(o));
                int cu = m_dq*8 + j2;
                ((uint*)mh)[m_u*32 + (cu ^ swz)] = hm;
                ((uint*)ml)[m_u*32 + (cu ^ swz)] = lm;
            }
        }
        __syncthreads();           // writes visible for next iteration
    }

    // ---- epilogue: row=(lane>>4)*4+r, col=ni*16+lr
    #pragma unroll
    for (int r = 0; r < 4; ++r) {
        float s = 0.f;
        #pragma unroll
        for (int ni = 0; ni < 4; ++ni) s += tanhf(acc[ni][r]) * wreg[ni];
        s += __shfl_xor(s, 1);
        s += __shfl_xor(s, 2);
        s += __shfl_xor(s, 4);
        s += __shfl_xor(s, 8);
        if (lr == 0) {
            int t = tt*64 + wid*16 + lg*4 + r;
            eij[((size_t)br*B_ + b)*T_ + t] = SR_ * s;
        }
    }
}

// ---------------------------------------------------------------------------
// K45: fused softmax + scale (unchanged).
// ---------------------------------------------------------------------------
__global__ __launch_bounds__(256) void k45_scale(
    const float* __restrict__ x1, const float* __restrict__ x2,
    const float* __restrict__ eij, float* __restrict__ out)
{
    __shared__ float sdata[256];
    __shared__ float wws[T_];

    const int tt = blockIdx.x;       // 0..15 : t-chunk of 64
    const int b  = blockIdx.y;       // 0..31
    const int br = blockIdx.z;       // 0..1
    const int tid = threadIdx.x;
    const float* e = eij + ((size_t)br*B_ + b) * T_;

    float v[4];
    float m = -1e30f;
    #pragma unroll
    for (int i = 0; i < 4; ++i) { v[i] = e[tid + i*256]; m = fmaxf(m, v[i]); }
    sdata[tid] = m; __syncthreads();
    for (int s = 128; s > 0; s >>= 1) {
        if (tid < s) sdata[tid] = fmaxf(sdata[tid], sdata[tid+s]);
        __syncthreads();
    }
    m = sdata[0]; __syncthreads();
    float ssum = 0.f;
    #pragma unroll
    for (int i = 0; i < 4; ++i) { v[i] = expf(v[i] - m); ssum += v[i]; }
    sdata[tid] = ssum; __syncthreads();
    for (int s = 128; s > 0; s >>= 1) {
        if (tid < s) sdata[tid] += sdata[tid+s];
        __syncthreads();
    }
    const float inv = 1.0f / (sdata[0] + EPS_ * expf(-m));
    #pragma unroll
    for (int i = 0; i < 4; ++i) wws[tid + i*256] = v[i] * inv;
    __syncthreads();

    const float* x = br ? x2 : x1;
    const size_t xb4 = ((size_t)b*T_ + (size_t)tt*64) * (D_/4);
    float* o = out + (size_t)br*B_*T_*D_;
    #pragma unroll
    for (int k = 0; k < 32; ++k) {
        int idx = k*256 + tid;           // 0..8191
        int tl  = idx >> 7;              // 0..63
        float w = wws[tt*64 + tl];
        float4 xv = ((const float4*)x)[xb4 + idx];
        float4 ov = {xv.x*w, xv.y*w, xv.z*w, xv.w*w};
        ((float4*)o)[xb4 + idx] = ov;
    }
}

// ---------------------------------------------------------------------------
extern "C" void kernel_launch(void* const* d_in, const int* in_sizes, int n_in,
                              void* d_out, int out_size, void* d_ws, size_t ws_size,
                              hipStream_t stream)
{
    const float* x1 = (const float*)d_in[0];
    const float* x2 = (const float*)d_in[1];
    const float* w1 = (const float*)d_in[2];
    const float* w2 = (const float*)d_in[3];
    const float* w3 = (const float*)d_in[4];
    const float* we = (const float*)d_in[5];
    float* out = (float*)d_out;
    float* ws  = (float*)d_ws;

    // workspace layout (floats)
    float* P   = ws;                             // TS_*B_*2*D_*U_ = 8,388,608
    float* M1  = P   + (size_t)TS_*B_*2*D_*U_;   // 1,048,576
    float* M2  = M1  + (size_t)B_*D_*U_;         // 1,048,576
    float* eij = M2  + (size_t)B_*D_*U_;         // 65,536

    k1_partials<<<dim3(8, TS_, B_), 256, 0, stream>>>(x1, x2, w2, w3, P);
    k1_combine <<<dim3((B_*D_*U_/4 + 255)/256), 256, 0, stream>>>(P, w1, M1, M2);
    k2_eij     <<<dim3(T_/TT_, B_, 2), 256, 0, stream>>>(x1, x2, M1, M2, we, eij);
    k45_scale  <<<dim3(16, B_, 2), 256, 0, stream>>>(x1, x2, eij, out);
}